// Round 17
// baseline (1129.032 us; speedup 1.0000x reference)
//
#include <hip/hip_runtime.h>
#include <math.h>

#define BATCH 65536
#define KIN   784
#define HD    768

typedef float f32x4 __attribute__((ext_vector_type(4)));
typedef short s16x8 __attribute__((ext_vector_type(8)));
typedef unsigned int __attribute__((address_space(3))) lds_u32;
typedef const unsigned int __attribute__((address_space(1))) glb_u32;

__device__ __forceinline__ float frelu(float x){ return x > 0.f ? x : 0.f; }

// packed bf16 convert: dst = {lo16=cvt(a), hi16=cvt(b)}
__device__ __forceinline__ unsigned int cvtpk(float a, float b){
    unsigned int r;
    asm("v_cvt_pk_bf16_f32 %0, %1, %2" : "=v"(r) : "v"(a), "v"(b));
    return r;
}
__device__ __forceinline__ unsigned short f2bf(float v){
    unsigned int u = __builtin_bit_cast(unsigned int, v);
    u += 0x7FFFu + ((u >> 16) & 1u);
    return (unsigned short)(u >> 16);
}
__device__ __forceinline__ float bf2f(unsigned short s){
    unsigned int u = ((unsigned int)s) << 16;
    return __builtin_bit_cast(float, u);
}
__device__ __forceinline__ void gload16(const void* g, void* l){
    __builtin_amdgcn_global_load_lds((glb_u32*)g, (lds_u32*)l, 16, 0, 0);
}

// ---------------------------------------------------------------------------
// x [B,784] fp32 -> xbf [B,800] bf16 (pad zeroed). One uint4 (8 elems)/thread.
// ---------------------------------------------------------------------------
__global__ __launch_bounds__(256)
void cvtX(const float* __restrict__ x, unsigned short* __restrict__ xbf)
{
    int idx = blockIdx.x * 256 + threadIdx.x;     // BATCH*100 total
    int row = idx / 100, c = (idx - row * 100) * 8;
    uint4 o = make_uint4(0, 0, 0, 0);
    if (c < KIN) {
        const float* p = x + (size_t)row * KIN + c;
        float4 a = *(const float4*)p;
        float4 b = *(const float4*)(p + 4);
        o.x = cvtpk(a.x, a.y); o.y = cvtpk(a.z, a.w);
        o.z = cvtpk(b.x, b.y); o.w = cvtpk(b.z, b.w);
    }
    *(uint4*)(xbf + (size_t)row * 800 + c) = o;
}

// ---------------------------------------------------------------------------
// feat = relu(hbf*scale + shift) -> fbf (bf16). 8 elems/thread.
// ---------------------------------------------------------------------------
__global__ __launch_bounds__(256)
void featBN(const unsigned short* __restrict__ hbf,
            const float* __restrict__ scale, const float* __restrict__ shift,
            unsigned short* __restrict__ fbf)
{
    int idx = blockIdx.x * 256 + threadIdx.x;     // BATCH*96 total
    int row = idx / 96, c = (idx - row * 96) * 8;
    s16x8 hv = *(const s16x8*)(hbf + (size_t)row * HD + c);
    float4 s0 = *(const float4*)(scale + c), s1 = *(const float4*)(scale + c + 4);
    float4 t0 = *(const float4*)(shift + c), t1 = *(const float4*)(shift + c + 4);
    float v[8];
    v[0] = frelu(bf2f((unsigned short)hv[0]) * s0.x + t0.x);
    v[1] = frelu(bf2f((unsigned short)hv[1]) * s0.y + t0.y);
    v[2] = frelu(bf2f((unsigned short)hv[2]) * s0.z + t0.z);
    v[3] = frelu(bf2f((unsigned short)hv[3]) * s0.w + t0.w);
    v[4] = frelu(bf2f((unsigned short)hv[4]) * s1.x + t1.x);
    v[5] = frelu(bf2f((unsigned short)hv[5]) * s1.y + t1.y);
    v[6] = frelu(bf2f((unsigned short)hv[6]) * s1.z + t1.z);
    v[7] = frelu(bf2f((unsigned short)hv[7]) * s1.w + t1.w);
    uint4 o;
    o.x = cvtpk(v[0], v[1]); o.y = cvtpk(v[2], v[3]);
    o.z = cvtpk(v[4], v[5]); o.w = cvtpk(v[6], v[7]);
    *(uint4*)(fbf + (size_t)row * HD + c) = o;
}

// ---------------------------------------------------------------------------
// Pre-tile W[K][N] fp32 -> bf16 per-(nb,t) 8KB chunks = exact swizzled LDS
// image: byte (r*64+p*16+e*2) = bf16 of W[t*32+s*8+e][nb*128+r], s=p^((r>>1)&3)
// ---------------------------------------------------------------------------
__global__ __launch_bounds__(256)
void tileW(const float* __restrict__ W, char* __restrict__ Wh, int K, int N, int NT)
{
    int chunk = blockIdx.x;
    int nb = chunk / NT, t = chunk - nb * NT;
    int tid = threadIdx.x;
    #pragma unroll
    for (int q = 0; q < 2; q++) {
        int idx = q * 256 + tid;
        int r = idx >> 2, p = idx & 3;
        int s = (p ^ ((r >> 1) & 3)) & 3;
        int kb = t * 32 + s * 8;
        int n = nb * 128 + r;
        s16x8 hv;
        #pragma unroll
        for (int e = 0; e < 8; e++) {
            int k = kb + e;
            float v = (k < K) ? W[(size_t)k * N + n] : 0.f;
            hv[e] = (short)f2bf(v);
        }
        *(s16x8*)(Wh + (size_t)chunk * 8192 + idx * 16) = hv;
    }
}

// ---- Wa[d] 768x64 -> 24 chunks of 4KB per domain (64-row swizzled image) ---
__global__ __launch_bounds__(256)
void tileWa(const float* __restrict__ Wa, char* __restrict__ WaC)
{
    int chunk = blockIdx.x;            // d*24 + t
    int d = chunk / 24, t = chunk - d * 24;
    int idx = threadIdx.x;
    int r = idx >> 2, p = idx & 3;     // r = expert col (0..63)
    int s = (p ^ ((r >> 1) & 3)) & 3;
    int kb = t * 32 + s * 8;
    s16x8 hv;
    #pragma unroll
    for (int e = 0; e < 8; e++)
        hv[e] = (short)f2bf(Wa[((size_t)d * HD + kb + e) * 64 + r]);
    *(s16x8*)(WaC + (size_t)chunk * 4096 + idx * 16) = hv;
}

// ---------------------------------------------------------------------------
// m97-shaped bf16 GEMM: BOTH operands staged via global_load_lds (A from a
// bf16 row-major array with per-lane pre-swizzled k-offsets; B from pre-tiled
// chunks). ZERO VALU in the K-loop. Single 16KB buffer, 2-barrier loop.
// MODE 0: A=xbf(KP=800); epilogue h(bf16) + fused BN column partials.
// MODE 1: A=fbf(KP=768); epilogue a=relu(acc+bd1); domacc += a @ Wd2.
// ---------------------------------------------------------------------------
template<int MODE>
__global__ __launch_bounds__(256, 3)
void gemm97(const unsigned short* __restrict__ Abf,
            const char* __restrict__ BhC,
            const float* __restrict__ bias,
            unsigned short* __restrict__ Hbf,
            const float* __restrict__ Wd2, double* __restrict__ domacc,
            float* __restrict__ sp1, float* __restrict__ sp2,
            int KP, int NT)
{
    __shared__ __align__(16) char sm[16384];      // A 8KB | B 8KB

    int bid = blockIdx.x;
    int wg = (bid & 7) * 384 + (bid >> 3);        // XCD-contiguous remap
    int mb = wg / 6, nb = wg - mb * 6;
    int m0 = mb << 7, n0 = nb << 7;

    int tid = threadIdx.x;
    int lane = tid & 63, wid = tid >> 6;
    int wr = wid >> 1, wc = wid & 1;
    int l15 = lane & 15, l4 = lane >> 4;

    int aoff[4], boff[4];
    #pragma unroll
    for (int f = 0; f < 4; f++) {
        int ra = wr * 64 + f * 16 + l15;
        aoff[f] = ra * 64 + (((l4 ^ (ra >> 1)) & 3) << 4);
        int rb = wc * 64 + f * 16 + l15;
        boff[f] = rb * 64 + (((l4 ^ (rb >> 1)) & 3) << 4);
    }

    // staging: idx = q*256+tid -> row r, phys slot p; source k-group s
    int ar[2], asl[2];
    #pragma unroll
    for (int q = 0; q < 2; q++) {
        int idx = q * 256 + tid;
        int r = idx >> 2, p = idx & 3;
        asl[q] = (p ^ ((r >> 1) & 3)) & 3;
        ar[q] = r;
    }

    f32x4 acc[4][4];
    #pragma unroll
    for (int i = 0; i < 4; i++)
        #pragma unroll
        for (int j = 0; j < 4; j++) acc[i][j] = (f32x4){0.f, 0.f, 0.f, 0.f};

    for (int t = 0; t < NT; t++) {
        #pragma unroll
        for (int q = 0; q < 2; q++) {             // stage A (pre-swizzled source)
            const unsigned short* src = Abf + (size_t)(m0 + ar[q]) * KP + t * 32 + asl[q] * 8;
            gload16(src, sm + (q * 256 + tid) * 16);
        }
        size_t cb = (size_t)(nb * NT + t) * 8192;
        #pragma unroll
        for (int q = 0; q < 2; q++) {             // stage B (linear chunk)
            int off = (q * 256 + tid) * 16;
            gload16(BhC + cb + off, sm + 8192 + off);
        }
        __syncthreads();                          // drains vmem+lds (compiler)
        s16x8 fah[4], fbh[4];
        #pragma unroll
        for (int f = 0; f < 4; f++) {
            fah[f] = *(const s16x8*)(sm + aoff[f]);
            fbh[f] = *(const s16x8*)(sm + 8192 + boff[f]);
        }
        #pragma unroll
        for (int i = 0; i < 4; i++)
            #pragma unroll
            for (int j = 0; j < 4; j++)
                acc[i][j] = __builtin_amdgcn_mfma_f32_16x16x32_bf16(fah[i], fbh[j], acc[i][j], 0, 0, 0);
        __syncthreads();                          // readers done before restage
    }

    if (MODE == 0) {
        float bc[4];
        #pragma unroll
        for (int f = 0; f < 4; f++) bc[f] = bias[n0 + wc * 64 + f * 16 + l15];
        float cs[4] = {0.f,0.f,0.f,0.f}, cq[4] = {0.f,0.f,0.f,0.f};
        #pragma unroll
        for (int i = 0; i < 4; i++) {
            int rowb = m0 + wr * 64 + i * 16 + l4 * 4;
            #pragma unroll
            for (int j2 = 0; j2 < 4; j2++) {
                unsigned short* hrow = Hbf + (size_t)(rowb + j2) * HD + n0 + wc * 64 + l15;
                #pragma unroll
                for (int f = 0; f < 4; f++) {
                    float v = acc[i][f][j2] + bc[f];
                    hrow[f * 16] = (unsigned short)cvtpk(v, v);   // lo16 = bf16(v)
                    cs[f] += v; cq[f] += v * v;
                }
            }
        }
        #pragma unroll
        for (int m = 16; m < 64; m <<= 1)
            #pragma unroll
            for (int f = 0; f < 4; f++) {
                cs[f] += __shfl_xor(cs[f], m, 64);
                cq[f] += __shfl_xor(cq[f], m, 64);
            }
        if (l4 == 0) {
            #pragma unroll
            for (int f = 0; f < 4; f++) {
                int col = n0 + wc * 64 + f * 16 + l15;
                sp1[(size_t)col * 1024 + mb * 2 + wr] = cs[f];
                sp2[(size_t)col * 1024 + mb * 2 + wr] = cq[f];
            }
        }
    } else {
        float bc[4], w2[4][3];
        #pragma unroll
        for (int f = 0; f < 4; f++) {
            int col = n0 + wc * 64 + f * 16 + l15;
            bc[f] = bias[col];
            w2[f][0] = Wd2[col * 3 + 0]; w2[f][1] = Wd2[col * 3 + 1]; w2[f][2] = Wd2[col * 3 + 2];
        }
        float s0[16], s1[16], s2[16];
        #pragma unroll
        for (int i = 0; i < 16; i++) { s0[i] = 0.f; s1[i] = 0.f; s2[i] = 0.f; }
        #pragma unroll
        for (int i = 0; i < 4; i++)
            #pragma unroll
            for (int j2 = 0; j2 < 4; j2++) {
                int idx = i * 4 + j2;
                #pragma unroll
                for (int f = 0; f < 4; f++) {
                    float v = frelu(acc[i][f][j2] + bc[f]);
                    s0[idx] += v * w2[f][0];
                    s1[idx] += v * w2[f][1];
                    s2[idx] += v * w2[f][2];
                }
            }
        #pragma unroll
        for (int m = 1; m < 16; m <<= 1) {
            #pragma unroll
            for (int i = 0; i < 16; i++) {
                s0[i] += __shfl_xor(s0[i], m, 64);
                s1[i] += __shfl_xor(s1[i], m, 64);
                s2[i] += __shfl_xor(s2[i], m, 64);
            }
        }
        if (l15 == 0) {
            #pragma unroll
            for (int i = 0; i < 16; i++) {
                int row = m0 + wr * 64 + (i >> 2) * 16 + l4 * 4 + (i & 3);
                atomicAdd(&domacc[(size_t)row * 3 + 0], (double)s0[i]);
                atomicAdd(&domacc[(size_t)row * 3 + 1], (double)s1[i]);
                atomicAdd(&domacc[(size_t)row * 3 + 2], (double)s2[i]);
            }
        }
    }
}

// ---- BN final: reduce 1024 fp32 partials per column in fp64 ----------------
__global__ __launch_bounds__(256)
void bnfinal(const float* __restrict__ sp1, const float* __restrict__ sp2,
             const float* __restrict__ gamma, const float* __restrict__ beta,
             float* __restrict__ scale, float* __restrict__ shift)
{
    int c = blockIdx.x, t = threadIdx.x;
    const float* p1 = sp1 + (size_t)c * 1024;
    const float* p2 = sp2 + (size_t)c * 1024;
    double S = (double)p1[t] + (double)p1[t + 256] + (double)p1[t + 512] + (double)p1[t + 768];
    double Q = (double)p2[t] + (double)p2[t + 256] + (double)p2[t + 512] + (double)p2[t + 768];
    #pragma unroll
    for (int m = 1; m < 64; m <<= 1) { S += __shfl_xor(S, m, 64); Q += __shfl_xor(Q, m, 64); }
    __shared__ double sd1[4], sd2[4];
    int w = t >> 6;
    if ((t & 63) == 0) { sd1[w] = S; sd2[w] = Q; }
    __syncthreads();
    if (t == 0) {
        double Sa = sd1[0] + sd1[1] + sd1[2] + sd1[3];
        double Qa = sd2[0] + sd2[1] + sd2[2] + sd2[3];
        double mu  = Sa * (1.0 / 65536.0);
        double var = Qa * (1.0 / 65536.0) - mu * mu;
        double inv = 1.0 / sqrt(var + 1e-5);
        double sc  = inv * (double)gamma[c];
        double sh  = (double)beta[c] - mu * sc;
        scale[c] = (float)sc;
        shift[c] = (float)sh;
    }
}

// ---- dom_out finalize pass A: write outdom, flag borderline rows -----------
__global__ __launch_bounds__(256)
void domfinal_a(const double* __restrict__ domacc, const float* __restrict__ bd2,
                float* __restrict__ outdom, int* __restrict__ fixmeta, int* __restrict__ fixlist)
{
    int r = blockIdx.x * 256 + threadIdx.x;
    double v0 = domacc[(size_t)r * 3 + 0] + (double)bd2[0];
    double v1 = domacc[(size_t)r * 3 + 1] + (double)bd2[1];
    double v2 = domacc[(size_t)r * 3 + 2] + (double)bd2[2];
    outdom[(size_t)r * 3 + 0] = (float)v0;
    outdom[(size_t)r * 3 + 1] = (float)v1;
    outdom[(size_t)r * 3 + 2] = (float)v2;
    double mx01 = v0 > v1 ? v0 : v1, mn01 = v0 > v1 ? v1 : v0;
    double best = mx01 > v2 ? mx01 : v2;
    double m2   = mx01 > v2 ? (mn01 > v2 ? mn01 : v2) : mx01;
    if (best - m2 < 1.5e-2) {
        int p = atomicAdd(fixmeta, 1);
        fixlist[p] = r;
    }
}

// ---- exact recompute of dom_out for flagged rows, FROM x (fp32) ------------
// r12 decomposition (FR=8, thread owns 3 cols) — proven best. NEW: weights
// flow through double-buffered LDS k-tiles (8 rows, issue-early/write-late):
// k-loop reads W from LDS (~6cy) instead of L2 (~200cy). r10-16 established
// the wall = ONE chunk's serial chain (1552 iters x ~365cy exposed latency);
// this attacks per-iter latency directly. Accumulation order unchanged.
#define FR 8
__global__ __launch_bounds__(256)
void fixrow_x(const int* __restrict__ fixmeta, const int* __restrict__ fixlist,
              const float* __restrict__ x, const float* __restrict__ W1,
              const float* __restrict__ b1,
              const float* __restrict__ scale, const float* __restrict__ shift,
              const float* __restrict__ Wd1, const float* __restrict__ bd1,
              const float* __restrict__ Wd2, const float* __restrict__ bd2,
              float* __restrict__ outdom)
{
    int nfix = fixmeta[0];
    __shared__ float xs[FR][788];
    __shared__ float ft[FR][HD];
    __shared__ float wt[2][8][776];      // W k-tile double buffer
    __shared__ float red[4][3];
    int tid = threadIdx.x;
    int n0 = tid * 3;
    // staging decomposition: idx = j*256+tid over 1536 float4 groups
    int skk[6], sc4[6];
    #pragma unroll
    for (int j = 0; j < 6; j++) {
        int idx = j * 256 + tid;
        skk[j] = idx / 192;
        sc4[j] = (idx - skk[j] * 192) * 4;
    }

    for (int base = blockIdx.x * FR; base < nfix; base += gridDim.x * FR) {
        int nr = nfix - base; if (nr > FR) nr = FR;
        __syncthreads();
        for (int i = tid; i < FR * KIN; i += 256) {
            int rr = i / KIN, c = i - rr * KIN;
            int row = fixlist[base + (rr < nr ? rr : nr - 1)];
            xs[rr][c] = x[(size_t)row * KIN + c];
        }
        // ---- stage 1: h = x @ W1, 98 k-tiles of 8 through LDS ----
        {
            float acc[FR][3];
            #pragma unroll
            for (int r = 0; r < FR; r++) { acc[r][0]=0.f; acc[r][1]=0.f; acc[r][2]=0.f; }
            float4 gl[6];
            #pragma unroll
            for (int j = 0; j < 6; j++)
                gl[j] = *(const float4*)(W1 + (size_t)skk[j] * HD + sc4[j]);
            #pragma unroll
            for (int j = 0; j < 6; j++)
                *(float4*)&wt[0][skk[j]][sc4[j]] = gl[j];
            __syncthreads();               // tile0 + xs visible
            for (int t = 0; t < 98; t++) {
                int buf = t & 1;
                if (t + 1 < 98) {
                    #pragma unroll
                    for (int j = 0; j < 6; j++)
                        gl[j] = *(const float4*)(W1 + (size_t)((t + 1) * 8 + skk[j]) * HD + sc4[j]);
                }
                float w0[8], w1[8], w2[8];
                #pragma unroll
                for (int kk = 0; kk < 8; kk++) {
                    w0[kk] = wt[buf][kk][n0];
                    w1[kk] = wt[buf][kk][n0 + 1];
                    w2[kk] = wt[buf][kk][n0 + 2];
                }
                #pragma unroll
                for (int r = 0; r < FR; r++) {
                    float4 xa = *(const float4*)&xs[r][t * 8];
                    float4 xb = *(const float4*)&xs[r][t * 8 + 4];
                    acc[r][0] += xa.x*w0[0]; acc[r][1] += xa.x*w1[0]; acc[r][2] += xa.x*w2[0];
                    acc[r][0] += xa.y*w0[1]; acc[r][1] += xa.y*w1[1]; acc[r][2] += xa.y*w2[1];
                    acc[r][0] += xa.z*w0[2]; acc[r][1] += xa.z*w1[2]; acc[r][2] += xa.z*w2[2];
                    acc[r][0] += xa.w*w0[3]; acc[r][1] += xa.w*w1[3]; acc[r][2] += xa.w*w2[3];
                    acc[r][0] += xb.x*w0[4]; acc[r][1] += xb.x*w1[4]; acc[r][2] += xb.x*w2[4];
                    acc[r][0] += xb.y*w0[5]; acc[r][1] += xb.y*w1[5]; acc[r][2] += xb.y*w2[5];
                    acc[r][0] += xb.z*w0[6]; acc[r][1] += xb.z*w1[6]; acc[r][2] += xb.z*w2[6];
                    acc[r][0] += xb.w*w0[7]; acc[r][1] += xb.w*w1[7]; acc[r][2] += xb.w*w2[7];
                }
                if (t + 1 < 98) {
                    #pragma unroll
                    for (int j = 0; j < 6; j++)
                        *(float4*)&wt[buf ^ 1][skk[j]][sc4[j]] = gl[j];
                }
                __syncthreads();
            }
            #pragma unroll
            for (int j = 0; j < 3; j++) {
                float bj = b1[n0 + j], scj = scale[n0 + j], shj = shift[n0 + j];
                #pragma unroll
                for (int r = 0; r < FR; r++)
                    ft[r][n0 + j] = frelu((acc[r][j] + bj) * scj + shj);
            }
        }
        __syncthreads();
        // ---- stage 2: dom = ft @ Wd1, 96 k-tiles of 8 through LDS ----
        float acc[FR][3];
        #pragma unroll
        for (int r = 0; r < FR; r++) { acc[r][0]=0.f; acc[r][1]=0.f; acc[r][2]=0.f; }
        {
            float4 gl[6];
            #pragma unroll
            for (int j = 0; j < 6; j++)
                gl[j] = *(const float4*)(Wd1 + (size_t)skk[j] * HD + sc4[j]);
            #pragma unroll
            for (int j = 0; j < 6; j++)
                *(float4*)&wt[0][skk[j]][sc4[j]] = gl[j];
            __syncthreads();
            for (int t = 0; t < 96; t++) {
                int buf = t & 1;
                if (t + 1 < 96) {
                    #pragma unroll
                    for (int j = 0; j < 6; j++)
                        gl[j] = *(const float4*)(Wd1 + (size_t)((t + 1) * 8 + skk[j]) * HD + sc4[j]);
                }
                float w0[8], w1[8], w2[8];
                #pragma unroll
                for (int kk = 0; kk < 8; kk++) {
                    w0[kk] = wt[buf][kk][n0];
                    w1[kk] = wt[buf][kk][n0 + 1];
                    w2[kk] = wt[buf][kk][n0 + 2];
                }
                #pragma unroll
                for (int r = 0; r < FR; r++) {
                    float4 xa = *(const float4*)&ft[r][t * 8];
                    float4 xb = *(const float4*)&ft[r][t * 8 + 4];
                    acc[r][0] += xa.x*w0[0]; acc[r][1] += xa.x*w1[0]; acc[r][2] += xa.x*w2[0];
                    acc[r][0] += xa.y*w0[1]; acc[r][1] += xa.y*w1[1]; acc[r][2] += xa.y*w2[1];
                    acc[r][0] += xa.z*w0[2]; acc[r][1] += xa.z*w1[2]; acc[r][2] += xa.z*w2[2];
                    acc[r][0] += xa.w*w0[3]; acc[r][1] += xa.w*w1[3]; acc[r][2] += xa.w*w2[3];
                    acc[r][0] += xb.x*w0[4]; acc[r][1] += xb.x*w1[4]; acc[r][2] += xb.x*w2[4];
                    acc[r][0] += xb.y*w0[5]; acc[r][1] += xb.y*w1[5]; acc[r][2] += xb.y*w2[5];
                    acc[r][0] += xb.z*w0[6]; acc[r][1] += xb.z*w1[6]; acc[r][2] += xb.z*w2[6];
                    acc[r][0] += xb.w*w0[7]; acc[r][1] += xb.w*w1[7]; acc[r][2] += xb.w*w2[7];
                }
                if (t + 1 < 96) {
                    #pragma unroll
                    for (int j = 0; j < 6; j++)
                        *(float4*)&wt[buf ^ 1][skk[j]][sc4[j]] = gl[j];
                }
                __syncthreads();
            }
        }
        // ---- final: relu + Wd2 projection, block reduce (as r12) ----
        float b0 = bd1[n0], b1v = bd1[n0 + 1], b2 = bd1[n0 + 2];
        float wa[3][3];
        #pragma unroll
        for (int i = 0; i < 3; i++)
            #pragma unroll
            for (int d = 0; d < 3; d++) wa[i][d] = Wd2[(n0 + i) * 3 + d];
        #pragma unroll
        for (int r = 0; r < FR; r++) {
            if (r >= nr) break;
            float h0 = frelu(acc[r][0] + b0);
            float h1 = frelu(acc[r][1] + b1v);
            float h2 = frelu(acc[r][2] + b2);
            float y0 = h0 * wa[0][0] + h1 * wa[1][0] + h2 * wa[2][0];
            float y1 = h0 * wa[0][1] + h1 * wa[1][1] + h2 * wa[2][1];
            float y2 = h0 * wa[0][2] + h1 * wa[1][2] + h2 * wa[2][2];
            #pragma unroll
            for (int m = 1; m < 64; m <<= 1) {
                y0 += __shfl_xor(y0, m, 64);
                y1 += __shfl_xor(y1, m, 64);
                y2 += __shfl_xor(y2, m, 64);
            }
            if ((tid & 63) == 0) { red[tid >> 6][0] = y0; red[tid >> 6][1] = y1; red[tid >> 6][2] = y2; }
            __syncthreads();
            if (tid == 0) {
                int row = fixlist[base + r];
                double v0 = (double)red[0][0] + red[1][0] + red[2][0] + red[3][0] + (double)bd2[0];
                double v1 = (double)red[0][1] + red[1][1] + red[2][1] + red[3][1] + (double)bd2[1];
                double v2 = (double)red[0][2] + red[1][2] + red[2][2] + red[3][2] + (double)bd2[2];
                outdom[(size_t)row * 3 + 0] = (float)v0;
                outdom[(size_t)row * 3 + 1] = (float)v1;
                outdom[(size_t)row * 3 + 2] = (float)v2;
            }
            __syncthreads();
        }
    }
}

// ---- pass B: argmax + bucket (block-aggregated atomics) --------------------
__global__ __launch_bounds__(256)
void domfinal_b(const float* __restrict__ outdom, int* __restrict__ cnt, int* __restrict__ lists)
{
    __shared__ int lcnt[3], base[3];
    int tid = threadIdx.x;
    if (tid < 3) lcnt[tid] = 0;
    __syncthreads();
    int r = blockIdx.x * 256 + tid;
    float v0 = outdom[(size_t)r * 3 + 0];
    float v1 = outdom[(size_t)r * 3 + 1];
    float v2 = outdom[(size_t)r * 3 + 2];
    int p = 0; float best = v0;
    if (v1 > best) { best = v1; p = 1; }
    if (v2 > best) { best = v2; p = 2; }
    int lpos = atomicAdd(&lcnt[p], 1);
    __syncthreads();
    if (tid < 3) base[tid] = atomicAdd(&cnt[tid], lcnt[tid]);
    __syncthreads();
    lists[(size_t)p * BATCH + base[p] + lpos] = r;
}

// ---- expert via MFMA: 128 gathered rows x 64(E) x K=768 per block ----------
__global__ __launch_bounds__(256)
void expert_mfma(const unsigned short* __restrict__ fbf,
                 const char* __restrict__ WaC,
                 const int* __restrict__ cnt, const int* __restrict__ lists,
                 const float* __restrict__ ba,
                 const float* __restrict__ Wb, const float* __restrict__ bb,
                 float* __restrict__ outs)
{
    __shared__ __align__(16) char sm[12288];   // A 8KB | B 4KB
    __shared__ float hid[128][66];
    __shared__ int rowidx[128];

    int d = blockIdx.y;
    int count = cnt[d];
    int start = blockIdx.x * 128;
    if (start >= count) return;
    int nrows = count - start; if (nrows > 128) nrows = 128;

    int tid = threadIdx.x;
    int lane = tid & 63, wid = tid >> 6;       // 4 waves stacked on M
    int l15 = lane & 15, l4 = lane >> 4;

    if (tid < 128) {
        int i = tid < nrows ? tid : nrows - 1;
        rowidx[tid] = lists[(size_t)d * BATCH + start + i];
    }
    __syncthreads();

    int asl[2], arow[2];
    #pragma unroll
    for (int q = 0; q < 2; q++) {
        int idx = q * 256 + tid;
        int r = idx >> 2, p = idx & 3;
        asl[q] = (p ^ ((r >> 1) & 3)) & 3;
        arow[q] = rowidx[r];
    }

    int aoff[2], boff[4];
    #pragma unroll
    for (int i2 = 0; i2 < 2; i2++) {
        int ra = wid * 32 + i2 * 16 + l15;
        aoff[i2] = ra * 64 + (((l4 ^ (ra >> 1)) & 3) << 4);
    }
    #pragma unroll
    for (int f = 0; f < 4; f++) {
        int rb = f * 16 + l15;
        boff[f] = rb * 64 + (((l4 ^ (rb >> 1)) & 3) << 4);
    }

    f32x4 acc[2][4];
    #pragma unroll
    for (int i = 0; i < 2; i++)
        #pragma unroll
        for (int j = 0; j < 4; j++) acc[i][j] = (f32x4){0.f, 0.f, 0.f, 0.f};

    for (int t = 0; t < 24; t++) {
        #pragma unroll
        for (int q = 0; q < 2; q++)
            gload16(fbf + (size_t)arow[q] * HD + t * 32 + asl[q] * 8,
                    sm + (q * 256 + tid) * 16);
        gload16(WaC + (size_t)(d * 24 + t) * 4096 + tid * 16, sm + 8192 + tid * 16);
        __syncthreads();
        s16x8 fa[2], fb[4];
        #pragma unroll
        for (int i2 = 0; i2 < 2; i2++) fa[i2] = *(const s16x8*)(sm + aoff[i2]);
        #pragma unroll
        for (int f = 0; f < 4; f++)    fb[f]  = *(const s16x8*)(sm + 8192 + boff[f]);
        #pragma unroll
        for (int i2 = 0; i2 < 2; i2++)
            #pragma unroll
            for (int f = 0; f < 4; f++)
                acc[i2][f] = __builtin_amdgcn_mfma_f32_16x16x32_bf16(fa[i2], fb[f], acc[i2][f], 0, 0, 0);
        __syncthreads();
    }

    #pragma unroll
    for (int i2 = 0; i2 < 2; i2++)
        #pragma unroll
        for (int f = 0; f < 4; f++) {
            int col = f * 16 + l15;
            float bav = ba[d * 64 + col];
            #pragma unroll
            for (int j = 0; j < 4; j++) {
                int row = wid * 32 + i2 * 16 + l4 * 4 + j;
                hid[row][col] = frelu(acc[i2][f][j] + bav);
            }
        }
    __syncthreads();

    for (int o = tid; o < 1280; o += 256) {
        int r2 = o / 10, c = o - r2 * 10;
        if (r2 < nrows) {
            float s = 0.f;
            #pragma unroll 16
            for (int l = 0; l < 64; l++) s += hid[r2][l] * Wb[((size_t)d * 64 + l) * 10 + c];
            outs[(size_t)rowidx[r2] * 10 + c] = s + bb[d * 10 + c];
        }
    }
}

// ---------------------------------------------------------------------------
extern "C" void kernel_launch(void* const* d_in, const int* in_sizes, int n_in,
                              void* d_out, int out_size, void* d_ws, size_t ws_size,
                              hipStream_t stream)
{
    const float* x     = (const float*)d_in[0];
    const float* W1    = (const float*)d_in[1];
    const float* b1    = (const float*)d_in[2];
    const float* gamma = (const float*)d_in[3];
    const float* beta  = (const float*)d_in[4];
    const float* Wd1   = (const float*)d_in[5];
    const float* bd1   = (const float*)d_in[6];
    const float* Wd2   = (const float*)d_in[7];
    const float* bd2   = (const float*)d_in[8];
    const float* Wa    = (const float*)d_in[9];
    const float* ba    = (const float*)d_in[10];
    const float* Wb    = (const float*)d_in[11];
    const float* bb    = (const float*)d_in[12];

    float* out    = (float*)d_out;
    float* outs   = out;
    float* outdom = out + (size_t)BATCH * 10;

    const int NT1 = 25, NT2 = 24;

    char* ws = (char*)d_ws;
    size_t off = 0;
    unsigned short* hbf = (unsigned short*)(ws + off); off += (size_t)BATCH * HD * 2;
    unsigned short* xbf = (unsigned short*)(ws + off); off += (size_t)BATCH * 800 * 2;
    unsigned short* fbf = xbf;   // alias: xbf dead after GEMM1; 768 <= 800 per row
    char*  W1hC   = ws + off;            off += (size_t)6 * NT1 * 8192;
    char*  Wd1hC  = ws + off;            off += (size_t)6 * NT2 * 8192;
    char*  WaC    = ws + off;            off += (size_t)3 * 24 * 4096;
    float* sp1    = (float*)(ws + off);  off += (size_t)HD * 1024 * 4;
    float* sp2    = (float*)(ws + off);  off += (size_t)HD * 1024 * 4;
    float* scale  = (float*)(ws + off);  off += HD * 4;
    float* shift  = (float*)(ws + off);  off += HD * 4;
    size_t zoff = off;
    double* domacc = (double*)(ws + off); off += (size_t)BATCH * 3 * 8;
    int*    cnt    = (int*)(ws + off);    off += 64;
    int*    fixmeta= (int*)(ws + off);    off += 64;
    size_t zbytes = off - zoff;
    int*    lists  = (int*)(ws + off);    off += (size_t)3 * BATCH * 4;
    int*    fixlist= (int*)(ws + off);    off += (size_t)BATCH * 4;

    hipMemsetAsync(ws + zoff, 0, zbytes, stream);

    tileW<<<6 * NT1, 256, 0, stream>>>(W1, W1hC, KIN, HD, NT1);
    tileW<<<6 * NT2, 256, 0, stream>>>(Wd1, Wd1hC, HD, HD, NT2);
    tileWa<<<72, 256, 0, stream>>>(Wa, WaC);
    cvtX<<<BATCH * 100 / 256, 256, 0, stream>>>(x, xbf);

    gemm97<0><<<3072, 256, 0, stream>>>(xbf, W1hC, b1, hbf,
                                        nullptr, nullptr, sp1, sp2, 800, NT1);
    bnfinal<<<HD, 256, 0, stream>>>(sp1, sp2, gamma, beta, scale, shift);
    featBN<<<BATCH * 96 / 256, 256, 0, stream>>>(hbf, scale, shift, fbf);
    gemm97<1><<<3072, 256, 0, stream>>>(fbf, Wd1hC, bd1, nullptr,
                                        Wd2, domacc, nullptr, nullptr, HD, NT2);
    domfinal_a<<<BATCH / 256, 256, 0, stream>>>(domacc, bd2, outdom, fixmeta, fixlist);
    fixrow_x<<<2048, 256, 0, stream>>>(fixmeta, fixlist, x, W1, b1, scale, shift,
                                       Wd1, bd1, Wd2, bd2, outdom);
    domfinal_b<<<BATCH / 256, 256, 0, stream>>>(outdom, cnt, lists);
    dim3 eg(512, 3);
    expert_mfma<<<eg, 256, 0, stream>>>(fbf, WaC, cnt, lists, ba, Wb, bb, outs);
}

// Round 18
// 748.061 us; speedup vs baseline: 1.5093x; 1.5093x over previous
//
#include <hip/hip_runtime.h>
#include <math.h>

#define BATCH 65536
#define KIN   784
#define HD    768
#define FR    8
#define FCAP  16384   // max flagged rows processed (observed nfix ~2-4k)

typedef float f32x4 __attribute__((ext_vector_type(4)));
typedef short s16x8 __attribute__((ext_vector_type(8)));
typedef unsigned int __attribute__((address_space(3))) lds_u32;
typedef const unsigned int __attribute__((address_space(1))) glb_u32;

__device__ __forceinline__ float frelu(float x){ return x > 0.f ? x : 0.f; }

__device__ __forceinline__ unsigned int cvtpk(float a, float b){
    unsigned int r;
    asm("v_cvt_pk_bf16_f32 %0, %1, %2" : "=v"(r) : "v"(a), "v"(b));
    return r;
}
__device__ __forceinline__ unsigned short f2bf(float v){
    unsigned int u = __builtin_bit_cast(unsigned int, v);
    u += 0x7FFFu + ((u >> 16) & 1u);
    return (unsigned short)(u >> 16);
}
__device__ __forceinline__ float bf2f(unsigned short s){
    unsigned int u = ((unsigned int)s) << 16;
    return __builtin_bit_cast(float, u);
}
__device__ __forceinline__ void gload16(const void* g, void* l){
    __builtin_amdgcn_global_load_lds((glb_u32*)g, (lds_u32*)l, 16, 0, 0);
}

// ---------------------------------------------------------------------------
// x [B,784] fp32 -> xbf [B,800] bf16 (pad zeroed).
// ---------------------------------------------------------------------------
__global__ __launch_bounds__(256)
void cvtX(const float* __restrict__ x, unsigned short* __restrict__ xbf)
{
    int idx = blockIdx.x * 256 + threadIdx.x;
    int row = idx / 100, c = (idx - row * 100) * 8;
    uint4 o = make_uint4(0, 0, 0, 0);
    if (c < KIN) {
        const float* p = x + (size_t)row * KIN + c;
        float4 a = *(const float4*)p;
        float4 b = *(const float4*)(p + 4);
        o.x = cvtpk(a.x, a.y); o.y = cvtpk(a.z, a.w);
        o.z = cvtpk(b.x, b.y); o.w = cvtpk(b.z, b.w);
    }
    *(uint4*)(xbf + (size_t)row * 800 + c) = o;
}

// ---------------------------------------------------------------------------
// feat = relu(hbf*scale + shift) -> fbf (bf16).
// ---------------------------------------------------------------------------
__global__ __launch_bounds__(256)
void featBN(const unsigned short* __restrict__ hbf,
            const float* __restrict__ scale, const float* __restrict__ shift,
            unsigned short* __restrict__ fbf)
{
    int idx = blockIdx.x * 256 + threadIdx.x;
    int row = idx / 96, c = (idx - row * 96) * 8;
    s16x8 hv = *(const s16x8*)(hbf + (size_t)row * HD + c);
    float4 s0 = *(const float4*)(scale + c), s1 = *(const float4*)(scale + c + 4);
    float4 t0 = *(const float4*)(shift + c), t1 = *(const float4*)(shift + c + 4);
    float v[8];
    v[0] = frelu(bf2f((unsigned short)hv[0]) * s0.x + t0.x);
    v[1] = frelu(bf2f((unsigned short)hv[1]) * s0.y + t0.y);
    v[2] = frelu(bf2f((unsigned short)hv[2]) * s0.z + t0.z);
    v[3] = frelu(bf2f((unsigned short)hv[3]) * s0.w + t0.w);
    v[4] = frelu(bf2f((unsigned short)hv[4]) * s1.x + t1.x);
    v[5] = frelu(bf2f((unsigned short)hv[5]) * s1.y + t1.y);
    v[6] = frelu(bf2f((unsigned short)hv[6]) * s1.z + t1.z);
    v[7] = frelu(bf2f((unsigned short)hv[7]) * s1.w + t1.w);
    uint4 o;
    o.x = cvtpk(v[0], v[1]); o.y = cvtpk(v[2], v[3]);
    o.z = cvtpk(v[4], v[5]); o.w = cvtpk(v[6], v[7]);
    *(uint4*)(fbf + (size_t)row * HD + c) = o;
}

// ---------------------------------------------------------------------------
// Pre-tile W[K][N] fp32 -> bf16 swizzled 8KB chunks (128-col tiles).
// ---------------------------------------------------------------------------
__global__ __launch_bounds__(256)
void tileW(const float* __restrict__ W, char* __restrict__ Wh, int K, int N, int NT)
{
    int chunk = blockIdx.x;
    int nb = chunk / NT, t = chunk - nb * NT;
    int tid = threadIdx.x;
    #pragma unroll
    for (int q = 0; q < 2; q++) {
        int idx = q * 256 + tid;
        int r = idx >> 2, p = idx & 3;
        int s = (p ^ ((r >> 1) & 3)) & 3;
        int kb = t * 32 + s * 8;
        int n = nb * 128 + r;
        s16x8 hv;
        #pragma unroll
        for (int e = 0; e < 8; e++) {
            int k = kb + e;
            float v = (k < K) ? W[(size_t)k * N + n] : 0.f;
            hv[e] = (short)f2bf(v);
        }
        *(s16x8*)(Wh + (size_t)chunk * 8192 + idx * 16) = hv;
    }
}

// ---- Wa[d] 768x64 -> 24 chunks of 4KB per domain (64-row swizzled image) ---
__global__ __launch_bounds__(256)
void tileWa(const float* __restrict__ Wa, char* __restrict__ WaC)
{
    int chunk = blockIdx.x;            // d*24 + t
    int d = chunk / 24, t = chunk - d * 24;
    int idx = threadIdx.x;
    int r = idx >> 2, p = idx & 3;
    int s = (p ^ ((r >> 1) & 3)) & 3;
    int kb = t * 32 + s * 8;
    s16x8 hv;
    #pragma unroll
    for (int e = 0; e < 8; e++)
        hv[e] = (short)f2bf(Wa[((size_t)d * HD + kb + e) * 64 + r]);
    *(s16x8*)(WaC + (size_t)chunk * 4096 + idx * 16) = hv;
}

// ---------------------------------------------------------------------------
// m97-shaped bf16 GEMM (unchanged from r16).
// ---------------------------------------------------------------------------
template<int MODE>
__global__ __launch_bounds__(256, 3)
void gemm97(const unsigned short* __restrict__ Abf,
            const char* __restrict__ BhC,
            const float* __restrict__ bias,
            unsigned short* __restrict__ Hbf,
            const float* __restrict__ Wd2, double* __restrict__ domacc,
            float* __restrict__ sp1, float* __restrict__ sp2,
            int KP, int NT)
{
    __shared__ __align__(16) char sm[16384];

    int bid = blockIdx.x;
    int wg = (bid & 7) * 384 + (bid >> 3);
    int mb = wg / 6, nb = wg - mb * 6;
    int m0 = mb << 7, n0 = nb << 7;

    int tid = threadIdx.x;
    int lane = tid & 63, wid = tid >> 6;
    int wr = wid >> 1, wc = wid & 1;
    int l15 = lane & 15, l4 = lane >> 4;

    int aoff[4], boff[4];
    #pragma unroll
    for (int f = 0; f < 4; f++) {
        int ra = wr * 64 + f * 16 + l15;
        aoff[f] = ra * 64 + (((l4 ^ (ra >> 1)) & 3) << 4);
        int rb = wc * 64 + f * 16 + l15;
        boff[f] = rb * 64 + (((l4 ^ (rb >> 1)) & 3) << 4);
    }

    int ar[2], asl[2];
    #pragma unroll
    for (int q = 0; q < 2; q++) {
        int idx = q * 256 + tid;
        int r = idx >> 2, p = idx & 3;
        asl[q] = (p ^ ((r >> 1) & 3)) & 3;
        ar[q] = r;
    }

    f32x4 acc[4][4];
    #pragma unroll
    for (int i = 0; i < 4; i++)
        #pragma unroll
        for (int j = 0; j < 4; j++) acc[i][j] = (f32x4){0.f, 0.f, 0.f, 0.f};

    for (int t = 0; t < NT; t++) {
        #pragma unroll
        for (int q = 0; q < 2; q++) {
            const unsigned short* src = Abf + (size_t)(m0 + ar[q]) * KP + t * 32 + asl[q] * 8;
            gload16(src, sm + (q * 256 + tid) * 16);
        }
        size_t cb = (size_t)(nb * NT + t) * 8192;
        #pragma unroll
        for (int q = 0; q < 2; q++) {
            int off = (q * 256 + tid) * 16;
            gload16(BhC + cb + off, sm + 8192 + off);
        }
        __syncthreads();
        s16x8 fah[4], fbh[4];
        #pragma unroll
        for (int f = 0; f < 4; f++) {
            fah[f] = *(const s16x8*)(sm + aoff[f]);
            fbh[f] = *(const s16x8*)(sm + 8192 + boff[f]);
        }
        #pragma unroll
        for (int i = 0; i < 4; i++)
            #pragma unroll
            for (int j = 0; j < 4; j++)
                acc[i][j] = __builtin_amdgcn_mfma_f32_16x16x32_bf16(fah[i], fbh[j], acc[i][j], 0, 0, 0);
        __syncthreads();
    }

    if (MODE == 0) {
        float bc[4];
        #pragma unroll
        for (int f = 0; f < 4; f++) bc[f] = bias[n0 + wc * 64 + f * 16 + l15];
        float cs[4] = {0.f,0.f,0.f,0.f}, cq[4] = {0.f,0.f,0.f,0.f};
        #pragma unroll
        for (int i = 0; i < 4; i++) {
            int rowb = m0 + wr * 64 + i * 16 + l4 * 4;
            #pragma unroll
            for (int j2 = 0; j2 < 4; j2++) {
                unsigned short* hrow = Hbf + (size_t)(rowb + j2) * HD + n0 + wc * 64 + l15;
                #pragma unroll
                for (int f = 0; f < 4; f++) {
                    float v = acc[i][f][j2] + bc[f];
                    hrow[f * 16] = (unsigned short)cvtpk(v, v);
                    cs[f] += v; cq[f] += v * v;
                }
            }
        }
        #pragma unroll
        for (int m = 16; m < 64; m <<= 1)
            #pragma unroll
            for (int f = 0; f < 4; f++) {
                cs[f] += __shfl_xor(cs[f], m, 64);
                cq[f] += __shfl_xor(cq[f], m, 64);
            }
        if (l4 == 0) {
            #pragma unroll
            for (int f = 0; f < 4; f++) {
                int col = n0 + wc * 64 + f * 16 + l15;
                sp1[(size_t)col * 1024 + mb * 2 + wr] = cs[f];
                sp2[(size_t)col * 1024 + mb * 2 + wr] = cq[f];
            }
        }
    } else {
        float bc[4], w2[4][3];
        #pragma unroll
        for (int f = 0; f < 4; f++) {
            int col = n0 + wc * 64 + f * 16 + l15;
            bc[f] = bias[col];
            w2[f][0] = Wd2[col * 3 + 0]; w2[f][1] = Wd2[col * 3 + 1]; w2[f][2] = Wd2[col * 3 + 2];
        }
        float s0[16], s1[16], s2[16];
        #pragma unroll
        for (int i = 0; i < 16; i++) { s0[i] = 0.f; s1[i] = 0.f; s2[i] = 0.f; }
        #pragma unroll
        for (int i = 0; i < 4; i++)
            #pragma unroll
            for (int j2 = 0; j2 < 4; j2++) {
                int idx = i * 4 + j2;
                #pragma unroll
                for (int f = 0; f < 4; f++) {
                    float v = frelu(acc[i][f][j2] + bc[f]);
                    s0[idx] += v * w2[f][0];
                    s1[idx] += v * w2[f][1];
                    s2[idx] += v * w2[f][2];
                }
            }
        #pragma unroll
        for (int m = 1; m < 16; m <<= 1) {
            #pragma unroll
            for (int i = 0; i < 16; i++) {
                s0[i] += __shfl_xor(s0[i], m, 64);
                s1[i] += __shfl_xor(s1[i], m, 64);
                s2[i] += __shfl_xor(s2[i], m, 64);
            }
        }
        if (l15 == 0) {
            #pragma unroll
            for (int i = 0; i < 16; i++) {
                int row = m0 + wr * 64 + (i >> 2) * 16 + l4 * 4 + (i & 3);
                atomicAdd(&domacc[(size_t)row * 3 + 0], (double)s0[i]);
                atomicAdd(&domacc[(size_t)row * 3 + 1], (double)s1[i]);
                atomicAdd(&domacc[(size_t)row * 3 + 2], (double)s2[i]);
            }
        }
    }
}

// ---- BN final: reduce 1024 fp32 partials per column in fp64 ----------------
__global__ __launch_bounds__(256)
void bnfinal(const float* __restrict__ sp1, const float* __restrict__ sp2,
             const float* __restrict__ gamma, const float* __restrict__ beta,
             float* __restrict__ scale, float* __restrict__ shift)
{
    int c = blockIdx.x, t = threadIdx.x;
    const float* p1 = sp1 + (size_t)c * 1024;
    const float* p2 = sp2 + (size_t)c * 1024;
    double S = (double)p1[t] + (double)p1[t + 256] + (double)p1[t + 512] + (double)p1[t + 768];
    double Q = (double)p2[t] + (double)p2[t + 256] + (double)p2[t + 512] + (double)p2[t + 768];
    #pragma unroll
    for (int m = 1; m < 64; m <<= 1) { S += __shfl_xor(S, m, 64); Q += __shfl_xor(Q, m, 64); }
    __shared__ double sd1[4], sd2[4];
    int w = t >> 6;
    if ((t & 63) == 0) { sd1[w] = S; sd2[w] = Q; }
    __syncthreads();
    if (t == 0) {
        double Sa = sd1[0] + sd1[1] + sd1[2] + sd1[3];
        double Qa = sd2[0] + sd2[1] + sd2[2] + sd2[3];
        double mu  = Sa * (1.0 / 65536.0);
        double var = Qa * (1.0 / 65536.0) - mu * mu;
        double inv = 1.0 / sqrt(var + 1e-5);
        double sc  = inv * (double)gamma[c];
        double sh  = (double)beta[c] - mu * sc;
        scale[c] = (float)sc;
        shift[c] = (float)sh;
    }
}

// ---- dom_out finalize pass A: write outdom, flag borderline rows -----------
__global__ __launch_bounds__(256)
void domfinal_a(const double* __restrict__ domacc, const float* __restrict__ bd2,
                float* __restrict__ outdom, int* __restrict__ fixmeta, int* __restrict__ fixlist)
{
    int r = blockIdx.x * 256 + threadIdx.x;
    double v0 = domacc[(size_t)r * 3 + 0] + (double)bd2[0];
    double v1 = domacc[(size_t)r * 3 + 1] + (double)bd2[1];
    double v2 = domacc[(size_t)r * 3 + 2] + (double)bd2[2];
    outdom[(size_t)r * 3 + 0] = (float)v0;
    outdom[(size_t)r * 3 + 1] = (float)v1;
    outdom[(size_t)r * 3 + 2] = (float)v2;
    double mx01 = v0 > v1 ? v0 : v1, mn01 = v0 > v1 ? v1 : v0;
    double best = mx01 > v2 ? mx01 : v2;
    double m2   = mx01 > v2 ? (mn01 > v2 ? mn01 : v2) : mx01;
    if (best - m2 < 1.5e-2) {
        int p = atomicAdd(fixmeta, 1);
        fixlist[p] = r;
    }
}

// ---------------------------------------------------------------------------
// fixrow split across BLOCKS (r10-r17 lesson: wall = one chunk's serial chain;
// intra-block splits all lost, so split at block granularity with the r12
// loop body verbatim). fx_s1: block=(chunk, k-quarter of 196), partial h via
// fp32 atomics into hfix. fx_s2: same for stage 2 (quarter 192) into h2fix,
// feat computed on-the-fly from hfix during staging. fx_fin: wave per row,
// relu + Wd2 projection. Chains: 1552 -> 196/192/12.
// ---------------------------------------------------------------------------
__global__ __launch_bounds__(256)
void fx_s1(const int* __restrict__ fixmeta, const int* __restrict__ fixlist,
           const float* __restrict__ x, const float* __restrict__ W1,
           float* __restrict__ hfix)
{
    int nfix = fixmeta[0]; if (nfix > FCAP) nfix = FCAP;
    __shared__ float xs[FR][200];
    int tid = threadIdx.x;
    int n0 = tid * 3;
    int p = blockIdx.x & 3, k0 = p * 196;
    int cstep = (gridDim.x >> 2) * FR;
    for (int base = (blockIdx.x >> 2) * FR; base < nfix; base += cstep) {
        int nr = nfix - base; if (nr > FR) nr = FR;
        __syncthreads();
        for (int i = tid; i < FR * 196; i += 256) {
            int rr = i / 196, cc = i - rr * 196;
            int row = fixlist[base + (rr < nr ? rr : nr - 1)];
            xs[rr][cc] = x[(size_t)row * KIN + k0 + cc];
        }
        __syncthreads();
        float acc[FR][3];
        #pragma unroll
        for (int r = 0; r < FR; r++) { acc[r][0]=0.f; acc[r][1]=0.f; acc[r][2]=0.f; }
        for (int kk = 0; kk < 196; kk++) {
            int k = k0 + kk;
            float w0 = W1[(size_t)k * HD + n0];
            float w1 = W1[(size_t)k * HD + n0 + 1];
            float w2 = W1[(size_t)k * HD + n0 + 2];
            #pragma unroll
            for (int r = 0; r < FR; r++) {
                float xv = xs[r][kk];
                acc[r][0] += xv * w0; acc[r][1] += xv * w1; acc[r][2] += xv * w2;
            }
        }
        for (int r = 0; r < nr; r++) {
            atomicAdd(&hfix[(size_t)(base + r) * HD + n0],     acc[r][0]);
            atomicAdd(&hfix[(size_t)(base + r) * HD + n0 + 1], acc[r][1]);
            atomicAdd(&hfix[(size_t)(base + r) * HD + n0 + 2], acc[r][2]);
        }
    }
}

__global__ __launch_bounds__(256)
void fx_s2(const int* __restrict__ fixmeta,
           const float* __restrict__ hfix,
           const float* __restrict__ b1, const float* __restrict__ scale,
           const float* __restrict__ shift,
           const float* __restrict__ Wd1, float* __restrict__ h2fix)
{
    int nfix = fixmeta[0]; if (nfix > FCAP) nfix = FCAP;
    __shared__ float ft[FR][196];
    int tid = threadIdx.x;
    int n0 = tid * 3;
    int p = blockIdx.x & 3, k0 = p * 192;
    int cstep = (gridDim.x >> 2) * FR;
    for (int base = (blockIdx.x >> 2) * FR; base < nfix; base += cstep) {
        int nr = nfix - base; if (nr > FR) nr = FR;
        __syncthreads();
        for (int i = tid; i < FR * 192; i += 256) {
            int rr = i / 192, cc = i - rr * 192;
            int k = k0 + cc;
            int fp = base + (rr < nr ? rr : nr - 1);
            ft[rr][cc] = frelu((hfix[(size_t)fp * HD + k] + b1[k]) * scale[k] + shift[k]);
        }
        __syncthreads();
        float acc[FR][3];
        #pragma unroll
        for (int r = 0; r < FR; r++) { acc[r][0]=0.f; acc[r][1]=0.f; acc[r][2]=0.f; }
        for (int kk = 0; kk < 192; kk++) {
            int k = k0 + kk;
            float w0 = Wd1[(size_t)k * HD + n0];
            float w1 = Wd1[(size_t)k * HD + n0 + 1];
            float w2 = Wd1[(size_t)k * HD + n0 + 2];
            #pragma unroll
            for (int r = 0; r < FR; r++) {
                float fv = ft[r][kk];
                acc[r][0] += fv * w0; acc[r][1] += fv * w1; acc[r][2] += fv * w2;
            }
        }
        for (int r = 0; r < nr; r++) {
            atomicAdd(&h2fix[(size_t)(base + r) * HD + n0],     acc[r][0]);
            atomicAdd(&h2fix[(size_t)(base + r) * HD + n0 + 1], acc[r][1]);
            atomicAdd(&h2fix[(size_t)(base + r) * HD + n0 + 2], acc[r][2]);
        }
    }
}

__global__ __launch_bounds__(256)
void fx_fin(const int* __restrict__ fixmeta, const int* __restrict__ fixlist,
            const float* __restrict__ h2fix,
            const float* __restrict__ bd1, const float* __restrict__ Wd2,
            const float* __restrict__ bd2, float* __restrict__ outdom)
{
    int nfix = fixmeta[0]; if (nfix > FCAP) nfix = FCAP;
    int tid = threadIdx.x, lane = tid & 63, wid = tid >> 6;
    for (int fp = blockIdx.x * 4 + wid; fp < nfix; fp += gridDim.x * 4) {
        int kb = lane * 12;
        float y0 = 0.f, y1 = 0.f, y2 = 0.f;
        #pragma unroll
        for (int j = 0; j < 12; j++) {
            int k = kb + j;
            float hh = frelu(h2fix[(size_t)fp * HD + k] + bd1[k]);
            y0 += hh * Wd2[k * 3 + 0];
            y1 += hh * Wd2[k * 3 + 1];
            y2 += hh * Wd2[k * 3 + 2];
        }
        #pragma unroll
        for (int m = 1; m < 64; m <<= 1) {
            y0 += __shfl_xor(y0, m, 64);
            y1 += __shfl_xor(y1, m, 64);
            y2 += __shfl_xor(y2, m, 64);
        }
        if (lane == 0) {
            int row = fixlist[fp];
            outdom[(size_t)row * 3 + 0] = y0 + bd2[0];
            outdom[(size_t)row * 3 + 1] = y1 + bd2[1];
            outdom[(size_t)row * 3 + 2] = y2 + bd2[2];
        }
    }
}

// ---- pass B: argmax + bucket (block-aggregated atomics) --------------------
__global__ __launch_bounds__(256)
void domfinal_b(const float* __restrict__ outdom, int* __restrict__ cnt, int* __restrict__ lists)
{
    __shared__ int lcnt[3], base[3];
    int tid = threadIdx.x;
    if (tid < 3) lcnt[tid] = 0;
    __syncthreads();
    int r = blockIdx.x * 256 + tid;
    float v0 = outdom[(size_t)r * 3 + 0];
    float v1 = outdom[(size_t)r * 3 + 1];
    float v2 = outdom[(size_t)r * 3 + 2];
    int p = 0; float best = v0;
    if (v1 > best) { best = v1; p = 1; }
    if (v2 > best) { best = v2; p = 2; }
    int lpos = atomicAdd(&lcnt[p], 1);
    __syncthreads();
    if (tid < 3) base[tid] = atomicAdd(&cnt[tid], lcnt[tid]);
    __syncthreads();
    lists[(size_t)p * BATCH + base[p] + lpos] = r;
}

// ---- expert via MFMA: 128 gathered rows x 64(E) x K=768 per block ----------
__global__ __launch_bounds__(256)
void expert_mfma(const unsigned short* __restrict__ fbf,
                 const char* __restrict__ WaC,
                 const int* __restrict__ cnt, const int* __restrict__ lists,
                 const float* __restrict__ ba,
                 const float* __restrict__ Wb, const float* __restrict__ bb,
                 float* __restrict__ outs)
{
    __shared__ __align__(16) char sm[12288];
    __shared__ float hid[128][66];
    __shared__ int rowidx[128];

    int d = blockIdx.y;
    int count = cnt[d];
    int start = blockIdx.x * 128;
    if (start >= count) return;
    int nrows = count - start; if (nrows > 128) nrows = 128;

    int tid = threadIdx.x;
    int lane = tid & 63, wid = tid >> 6;
    int l15 = lane & 15, l4 = lane >> 4;

    if (tid < 128) {
        int i = tid < nrows ? tid : nrows - 1;
        rowidx[tid] = lists[(size_t)d * BATCH + start + i];
    }
    __syncthreads();

    int asl[2], arow[2];
    #pragma unroll
    for (int q = 0; q < 2; q++) {
        int idx = q * 256 + tid;
        int r = idx >> 2, p = idx & 3;
        asl[q] = (p ^ ((r >> 1) & 3)) & 3;
        arow[q] = rowidx[r];
    }

    int aoff[2], boff[4];
    #pragma unroll
    for (int i2 = 0; i2 < 2; i2++) {
        int ra = wid * 32 + i2 * 16 + l15;
        aoff[i2] = ra * 64 + (((l4 ^ (ra >> 1)) & 3) << 4);
    }
    #pragma unroll
    for (int f = 0; f < 4; f++) {
        int rb = f * 16 + l15;
        boff[f] = rb * 64 + (((l4 ^ (rb >> 1)) & 3) << 4);
    }

    f32x4 acc[2][4];
    #pragma unroll
    for (int i = 0; i < 2; i++)
        #pragma unroll
        for (int j = 0; j < 4; j++) acc[i][j] = (f32x4){0.f, 0.f, 0.f, 0.f};

    for (int t = 0; t < 24; t++) {
        #pragma unroll
        for (int q = 0; q < 2; q++)
            gload16(fbf + (size_t)arow[q] * HD + t * 32 + asl[q] * 8,
                    sm + (q * 256 + tid) * 16);
        gload16(WaC + (size_t)(d * 24 + t) * 4096 + tid * 16, sm + 8192 + tid * 16);
        __syncthreads();
        s16x8 fa[2], fb[4];
        #pragma unroll
        for (int i2 = 0; i2 < 2; i2++) fa[i2] = *(const s16x8*)(sm + aoff[i2]);
        #pragma unroll
        for (int f = 0; f < 4; f++)    fb[f]  = *(const s16x8*)(sm + 8192 + boff[f]);
        #pragma unroll
        for (int i2 = 0; i2 < 2; i2++)
            #pragma unroll
            for (int f = 0; f < 4; f++)
                acc[i2][f] = __builtin_amdgcn_mfma_f32_16x16x32_bf16(fa[i2], fb[f], acc[i2][f], 0, 0, 0);
        __syncthreads();
    }

    #pragma unroll
    for (int i2 = 0; i2 < 2; i2++)
        #pragma unroll
        for (int f = 0; f < 4; f++) {
            int col = f * 16 + l15;
            float bav = ba[d * 64 + col];
            #pragma unroll
            for (int j = 0; j < 4; j++) {
                int row = wid * 32 + i2 * 16 + l4 * 4 + j;
                hid[row][col] = frelu(acc[i2][f][j] + bav);
            }
        }
    __syncthreads();

    for (int o = tid; o < 1280; o += 256) {
        int r2 = o / 10, c = o - r2 * 10;
        if (r2 < nrows) {
            float s = 0.f;
            #pragma unroll 16
            for (int l = 0; l < 64; l++) s += hid[r2][l] * Wb[((size_t)d * 64 + l) * 10 + c];
            outs[(size_t)rowidx[r2] * 10 + c] = s + bb[d * 10 + c];
        }
    }
}

// ---------------------------------------------------------------------------
extern "C" void kernel_launch(void* const* d_in, const int* in_sizes, int n_in,
                              void* d_out, int out_size, void* d_ws, size_t ws_size,
                              hipStream_t stream)
{
    const float* x     = (const float*)d_in[0];
    const float* W1    = (const float*)d_in[1];
    const float* b1    = (const float*)d_in[2];
    const float* gamma = (const float*)d_in[3];
    const float* beta  = (const float*)d_in[4];
    const float* Wd1   = (const float*)d_in[5];
    const float* bd1   = (const float*)d_in[6];
    const float* Wd2   = (const float*)d_in[7];
    const float* bd2   = (const float*)d_in[8];
    const float* Wa    = (const float*)d_in[9];
    const float* ba    = (const float*)d_in[10];
    const float* Wb    = (const float*)d_in[11];
    const float* bb    = (const float*)d_in[12];

    float* out    = (float*)d_out;
    float* outs   = out;
    float* outdom = out + (size_t)BATCH * 10;

    const int NT1 = 25, NT2 = 24;

    char* ws = (char*)d_ws;
    size_t off = 0;
    unsigned short* hbf = (unsigned short*)(ws + off); off += (size_t)BATCH * HD * 2;
    unsigned short* xbf = (unsigned short*)(ws + off); off += (size_t)BATCH * 800 * 2;
    unsigned short* fbf = xbf;   // alias: xbf dead after GEMM1
    // hbf (100.66 MB) is dead after featBN; reuse as hfix+h2fix (2*FCAP*768*4B, same size)
    float* hfix  = (float*)hbf;
    float* h2fix = hfix + (size_t)FCAP * HD;
    char*  W1hC   = ws + off;            off += (size_t)6 * NT1 * 8192;
    char*  Wd1hC  = ws + off;            off += (size_t)6 * NT2 * 8192;
    char*  WaC    = ws + off;            off += (size_t)3 * 24 * 4096;
    float* sp1    = (float*)(ws + off);  off += (size_t)HD * 1024 * 4;
    float* sp2    = (float*)(ws + off);  off += (size_t)HD * 1024 * 4;
    float* scale  = (float*)(ws + off);  off += HD * 4;
    float* shift  = (float*)(ws + off);  off += HD * 4;
    size_t zoff = off;
    double* domacc = (double*)(ws + off); off += (size_t)BATCH * 3 * 8;
    int*    cnt    = (int*)(ws + off);    off += 64;
    int*    fixmeta= (int*)(ws + off);    off += 64;
    size_t zbytes = off - zoff;
    int*    lists  = (int*)(ws + off);    off += (size_t)3 * BATCH * 4;
    int*    fixlist= (int*)(ws + off);    off += (size_t)BATCH * 4;

    hipMemsetAsync(ws + zoff, 0, zbytes, stream);

    tileW<<<6 * NT1, 256, 0, stream>>>(W1, W1hC, KIN, HD, NT1);
    tileW<<<6 * NT2, 256, 0, stream>>>(Wd1, Wd1hC, HD, HD, NT2);
    tileWa<<<72, 256, 0, stream>>>(Wa, WaC);
    cvtX<<<BATCH * 100 / 256, 256, 0, stream>>>(x, xbf);

    gemm97<0><<<3072, 256, 0, stream>>>(xbf, W1hC, b1, hbf,
                                        nullptr, nullptr, sp1, sp2, 800, NT1);
    bnfinal<<<HD, 256, 0, stream>>>(sp1, sp2, gamma, beta, scale, shift);
    featBN<<<BATCH * 96 / 256, 256, 0, stream>>>(hbf, scale, shift, fbf);
    // hbf now dead -> zero hfix/h2fix for the atomic partial sums
    hipMemsetAsync(hfix, 0, (size_t)2 * FCAP * HD * 4, stream);
    gemm97<1><<<3072, 256, 0, stream>>>(fbf, Wd1hC, bd1, nullptr,
                                        Wd2, domacc, nullptr, nullptr, HD, NT2);
    domfinal_a<<<BATCH / 256, 256, 0, stream>>>(domacc, bd2, outdom, fixmeta, fixlist);
    fx_s1<<<8192, 256, 0, stream>>>(fixmeta, fixlist, x, W1, hfix);
    fx_s2<<<8192, 256, 0, stream>>>(fixmeta, hfix, b1, scale, shift, Wd1, h2fix);
    fx_fin<<<512, 256, 0, stream>>>(fixmeta, fixlist, h2fix, bd1, Wd2, bd2, outdom);
    domfinal_b<<<BATCH / 256, 256, 0, stream>>>(outdom, cnt, lists);
    dim3 eg(512, 3);
    expert_mfma<<<eg, 256, 0, stream>>>(fbf, WaC, cnt, lists, ba, Wb, bb, outs);
}

// Round 19
// 742.164 us; speedup vs baseline: 1.5213x; 1.0079x over previous
//
#include <hip/hip_runtime.h>
#include <math.h>

#define BATCH 65536
#define KIN   784
#define HD    768
#define FR    8
#define FCAP  16384   // max flagged rows processed (observed nfix ~2-4k)

typedef float f32x4 __attribute__((ext_vector_type(4)));
typedef short s16x8 __attribute__((ext_vector_type(8)));
typedef unsigned int __attribute__((address_space(3))) lds_u32;
typedef const unsigned int __attribute__((address_space(1))) glb_u32;

__device__ __forceinline__ float frelu(float x){ return x > 0.f ? x : 0.f; }

__device__ __forceinline__ unsigned int cvtpk(float a, float b){
    unsigned int r;
    asm("v_cvt_pk_bf16_f32 %0, %1, %2" : "=v"(r) : "v"(a), "v"(b));
    return r;
}
__device__ __forceinline__ unsigned short f2bf(float v){
    unsigned int u = __builtin_bit_cast(unsigned int, v);
    u += 0x7FFFu + ((u >> 16) & 1u);
    return (unsigned short)(u >> 16);
}
__device__ __forceinline__ float bf2f(unsigned short s){
    unsigned int u = ((unsigned int)s) << 16;
    return __builtin_bit_cast(float, u);
}
__device__ __forceinline__ void gload16(const void* g, void* l){
    __builtin_amdgcn_global_load_lds((glb_u32*)g, (lds_u32*)l, 16, 0, 0);
}

// ---------------------------------------------------------------------------
// x [B,784] fp32 -> xbf [B,800] bf16 (pad zeroed).
// ---------------------------------------------------------------------------
__global__ __launch_bounds__(256)
void cvtX(const float* __restrict__ x, unsigned short* __restrict__ xbf)
{
    int idx = blockIdx.x * 256 + threadIdx.x;
    int row = idx / 100, c = (idx - row * 100) * 8;
    uint4 o = make_uint4(0, 0, 0, 0);
    if (c < KIN) {
        const float* p = x + (size_t)row * KIN + c;
        float4 a = *(const float4*)p;
        float4 b = *(const float4*)(p + 4);
        o.x = cvtpk(a.x, a.y); o.y = cvtpk(a.z, a.w);
        o.z = cvtpk(b.x, b.y); o.w = cvtpk(b.z, b.w);
    }
    *(uint4*)(xbf + (size_t)row * 800 + c) = o;
}

// ---------------------------------------------------------------------------
// feat = relu(hbf*scale + shift) -> fbf (bf16).
// ---------------------------------------------------------------------------
__global__ __launch_bounds__(256)
void featBN(const unsigned short* __restrict__ hbf,
            const float* __restrict__ scale, const float* __restrict__ shift,
            unsigned short* __restrict__ fbf)
{
    int idx = blockIdx.x * 256 + threadIdx.x;
    int row = idx / 96, c = (idx - row * 96) * 8;
    s16x8 hv = *(const s16x8*)(hbf + (size_t)row * HD + c);
    float4 s0 = *(const float4*)(scale + c), s1 = *(const float4*)(scale + c + 4);
    float4 t0 = *(const float4*)(shift + c), t1 = *(const float4*)(shift + c + 4);
    float v[8];
    v[0] = frelu(bf2f((unsigned short)hv[0]) * s0.x + t0.x);
    v[1] = frelu(bf2f((unsigned short)hv[1]) * s0.y + t0.y);
    v[2] = frelu(bf2f((unsigned short)hv[2]) * s0.z + t0.z);
    v[3] = frelu(bf2f((unsigned short)hv[3]) * s0.w + t0.w);
    v[4] = frelu(bf2f((unsigned short)hv[4]) * s1.x + t1.x);
    v[5] = frelu(bf2f((unsigned short)hv[5]) * s1.y + t1.y);
    v[6] = frelu(bf2f((unsigned short)hv[6]) * s1.z + t1.z);
    v[7] = frelu(bf2f((unsigned short)hv[7]) * s1.w + t1.w);
    uint4 o;
    o.x = cvtpk(v[0], v[1]); o.y = cvtpk(v[2], v[3]);
    o.z = cvtpk(v[4], v[5]); o.w = cvtpk(v[6], v[7]);
    *(uint4*)(fbf + (size_t)row * HD + c) = o;
}

// ---------------------------------------------------------------------------
// Pre-tile W[K][N] fp32 -> bf16 swizzled 8KB chunks (128-col tiles).
// ---------------------------------------------------------------------------
__global__ __launch_bounds__(256)
void tileW(const float* __restrict__ W, char* __restrict__ Wh, int K, int N, int NT)
{
    int chunk = blockIdx.x;
    int nb = chunk / NT, t = chunk - nb * NT;
    int tid = threadIdx.x;
    #pragma unroll
    for (int q = 0; q < 2; q++) {
        int idx = q * 256 + tid;
        int r = idx >> 2, p = idx & 3;
        int s = (p ^ ((r >> 1) & 3)) & 3;
        int kb = t * 32 + s * 8;
        int n = nb * 128 + r;
        s16x8 hv;
        #pragma unroll
        for (int e = 0; e < 8; e++) {
            int k = kb + e;
            float v = (k < K) ? W[(size_t)k * N + n] : 0.f;
            hv[e] = (short)f2bf(v);
        }
        *(s16x8*)(Wh + (size_t)chunk * 8192 + idx * 16) = hv;
    }
}

// ---- Wa[d] 768x64 -> 24 chunks of 4KB per domain (64-row swizzled image) ---
__global__ __launch_bounds__(256)
void tileWa(const float* __restrict__ Wa, char* __restrict__ WaC)
{
    int chunk = blockIdx.x;            // d*24 + t
    int d = chunk / 24, t = chunk - d * 24;
    int idx = threadIdx.x;
    int r = idx >> 2, p = idx & 3;
    int s = (p ^ ((r >> 1) & 3)) & 3;
    int kb = t * 32 + s * 8;
    s16x8 hv;
    #pragma unroll
    for (int e = 0; e < 8; e++)
        hv[e] = (short)f2bf(Wa[((size_t)d * HD + kb + e) * 64 + r]);
    *(s16x8*)(WaC + (size_t)chunk * 4096 + idx * 16) = hv;
}

// ---------------------------------------------------------------------------
// m97-shaped bf16 GEMM, now 2-PHASE DOUBLE-BUFFERED (T3 minimum): tile t+1's
// global_load_lds issued BEFORE computing tile t; ONE barrier per iteration
// (drains vmcnt -> t+1 landed, and confirms all readers of buf done before it
// is overwritten next iter). r18 profile: old stage-then-drain loop exposed a
// full load round-trip every iter (gemm 216us, MfmaUtil 14%).
// MODE 0: A=xbf(KP=800); epilogue h(bf16) + fused BN column partials.
// MODE 1: A=fbf(KP=768); epilogue a=relu(acc+bd1); domacc += a @ Wd2.
// ---------------------------------------------------------------------------
template<int MODE>
__global__ __launch_bounds__(256, 3)
void gemm97(const unsigned short* __restrict__ Abf,
            const char* __restrict__ BhC,
            const float* __restrict__ bias,
            unsigned short* __restrict__ Hbf,
            const float* __restrict__ Wd2, double* __restrict__ domacc,
            float* __restrict__ sp1, float* __restrict__ sp2,
            int KP, int NT)
{
    __shared__ __align__(16) char sm[32768];  // A dbuf 2x8KB | B dbuf 2x8KB

    int bid = blockIdx.x;
    int wg = (bid & 7) * 384 + (bid >> 3);
    int mb = wg / 6, nb = wg - mb * 6;
    int m0 = mb << 7, n0 = nb << 7;

    int tid = threadIdx.x;
    int lane = tid & 63, wid = tid >> 6;
    int wr = wid >> 1, wc = wid & 1;
    int l15 = lane & 15, l4 = lane >> 4;

    int aoff[4], boff[4];
    #pragma unroll
    for (int f = 0; f < 4; f++) {
        int ra = wr * 64 + f * 16 + l15;
        aoff[f] = ra * 64 + (((l4 ^ (ra >> 1)) & 3) << 4);
        int rb = wc * 64 + f * 16 + l15;
        boff[f] = rb * 64 + (((l4 ^ (rb >> 1)) & 3) << 4);
    }

    int ar[2], asl[2];
    #pragma unroll
    for (int q = 0; q < 2; q++) {
        int idx = q * 256 + tid;
        int r = idx >> 2, p = idx & 3;
        asl[q] = (p ^ ((r >> 1) & 3)) & 3;
        ar[q] = r;
    }

    f32x4 acc[4][4];
    #pragma unroll
    for (int i = 0; i < 4; i++)
        #pragma unroll
        for (int j = 0; j < 4; j++) acc[i][j] = (f32x4){0.f, 0.f, 0.f, 0.f};

    // prologue: stage tile 0 into buf 0
    #pragma unroll
    for (int q = 0; q < 2; q++) {
        const unsigned short* src = Abf + (size_t)(m0 + ar[q]) * KP + asl[q] * 8;
        gload16(src, sm + (q * 256 + tid) * 16);
    }
    {
        size_t cb = (size_t)(nb * NT) * 8192;
        #pragma unroll
        for (int q = 0; q < 2; q++) {
            int off = (q * 256 + tid) * 16;
            gload16(BhC + cb + off, sm + 16384 + off);
        }
    }
    __syncthreads();

    int buf = 0;
    for (int t = 0; t < NT; t++) {
        if (t + 1 < NT) {                       // issue NEXT tile into other buf
            int nb2 = (buf ^ 1) << 13;
            #pragma unroll
            for (int q = 0; q < 2; q++) {
                const unsigned short* src = Abf + (size_t)(m0 + ar[q]) * KP + (t + 1) * 32 + asl[q] * 8;
                gload16(src, sm + nb2 + (q * 256 + tid) * 16);
            }
            size_t cb = (size_t)(nb * NT + t + 1) * 8192;
            #pragma unroll
            for (int q = 0; q < 2; q++) {
                int off = (q * 256 + tid) * 16;
                gload16(BhC + cb + off, sm + 16384 + nb2 + off);
            }
        }
        const char* ab = sm + (buf << 13);
        const char* bb2 = sm + 16384 + (buf << 13);
        s16x8 fah[4], fbh[4];
        #pragma unroll
        for (int f = 0; f < 4; f++) {
            fah[f] = *(const s16x8*)(ab + aoff[f]);
            fbh[f] = *(const s16x8*)(bb2 + boff[f]);
        }
        #pragma unroll
        for (int i = 0; i < 4; i++)
            #pragma unroll
            for (int j = 0; j < 4; j++)
                acc[i][j] = __builtin_amdgcn_mfma_f32_16x16x32_bf16(fah[i], fbh[j], acc[i][j], 0, 0, 0);
        __syncthreads();    // drains vmcnt (next tile landed) + readers done
        buf ^= 1;
    }

    if (MODE == 0) {
        float bc[4];
        #pragma unroll
        for (int f = 0; f < 4; f++) bc[f] = bias[n0 + wc * 64 + f * 16 + l15];
        float cs[4] = {0.f,0.f,0.f,0.f}, cq[4] = {0.f,0.f,0.f,0.f};
        #pragma unroll
        for (int i = 0; i < 4; i++) {
            int rowb = m0 + wr * 64 + i * 16 + l4 * 4;
            #pragma unroll
            for (int j2 = 0; j2 < 4; j2++) {
                unsigned short* hrow = Hbf + (size_t)(rowb + j2) * HD + n0 + wc * 64 + l15;
                #pragma unroll
                for (int f = 0; f < 4; f++) {
                    float v = acc[i][f][j2] + bc[f];
                    hrow[f * 16] = (unsigned short)cvtpk(v, v);
                    cs[f] += v; cq[f] += v * v;
                }
            }
        }
        #pragma unroll
        for (int m = 16; m < 64; m <<= 1)
            #pragma unroll
            for (int f = 0; f < 4; f++) {
                cs[f] += __shfl_xor(cs[f], m, 64);
                cq[f] += __shfl_xor(cq[f], m, 64);
            }
        if (l4 == 0) {
            #pragma unroll
            for (int f = 0; f < 4; f++) {
                int col = n0 + wc * 64 + f * 16 + l15;
                sp1[(size_t)col * 1024 + mb * 2 + wr] = cs[f];
                sp2[(size_t)col * 1024 + mb * 2 + wr] = cq[f];
            }
        }
    } else {
        float bc[4], w2[4][3];
        #pragma unroll
        for (int f = 0; f < 4; f++) {
            int col = n0 + wc * 64 + f * 16 + l15;
            bc[f] = bias[col];
            w2[f][0] = Wd2[col * 3 + 0]; w2[f][1] = Wd2[col * 3 + 1]; w2[f][2] = Wd2[col * 3 + 2];
        }
        float s0[16], s1[16], s2[16];
        #pragma unroll
        for (int i = 0; i < 16; i++) { s0[i] = 0.f; s1[i] = 0.f; s2[i] = 0.f; }
        #pragma unroll
        for (int i = 0; i < 4; i++)
            #pragma unroll
            for (int j2 = 0; j2 < 4; j2++) {
                int idx = i * 4 + j2;
                #pragma unroll
                for (int f = 0; f < 4; f++) {
                    float v = frelu(acc[i][f][j2] + bc[f]);
                    s0[idx] += v * w2[f][0];
                    s1[idx] += v * w2[f][1];
                    s2[idx] += v * w2[f][2];
                }
            }
        #pragma unroll
        for (int m = 1; m < 16; m <<= 1) {
            #pragma unroll
            for (int i = 0; i < 16; i++) {
                s0[i] += __shfl_xor(s0[i], m, 64);
                s1[i] += __shfl_xor(s1[i], m, 64);
                s2[i] += __shfl_xor(s2[i], m, 64);
            }
        }
        if (l15 == 0) {
            #pragma unroll
            for (int i = 0; i < 16; i++) {
                int row = m0 + wr * 64 + (i >> 2) * 16 + l4 * 4 + (i & 3);
                atomicAdd(&domacc[(size_t)row * 3 + 0], (double)s0[i]);
                atomicAdd(&domacc[(size_t)row * 3 + 1], (double)s1[i]);
                atomicAdd(&domacc[(size_t)row * 3 + 2], (double)s2[i]);
            }
        }
    }
}

// ---- BN final: reduce 1024 fp32 partials per column in fp64 ----------------
__global__ __launch_bounds__(256)
void bnfinal(const float* __restrict__ sp1, const float* __restrict__ sp2,
             const float* __restrict__ gamma, const float* __restrict__ beta,
             float* __restrict__ scale, float* __restrict__ shift)
{
    int c = blockIdx.x, t = threadIdx.x;
    const float* p1 = sp1 + (size_t)c * 1024;
    const float* p2 = sp2 + (size_t)c * 1024;
    double S = (double)p1[t] + (double)p1[t + 256] + (double)p1[t + 512] + (double)p1[t + 768];
    double Q = (double)p2[t] + (double)p2[t + 256] + (double)p2[t + 512] + (double)p2[t + 768];
    #pragma unroll
    for (int m = 1; m < 64; m <<= 1) { S += __shfl_xor(S, m, 64); Q += __shfl_xor(Q, m, 64); }
    __shared__ double sd1[4], sd2[4];
    int w = t >> 6;
    if ((t & 63) == 0) { sd1[w] = S; sd2[w] = Q; }
    __syncthreads();
    if (t == 0) {
        double Sa = sd1[0] + sd1[1] + sd1[2] + sd1[3];
        double Qa = sd2[0] + sd2[1] + sd2[2] + sd2[3];
        double mu  = Sa * (1.0 / 65536.0);
        double var = Qa * (1.0 / 65536.0) - mu * mu;
        double inv = 1.0 / sqrt(var + 1e-5);
        double sc  = inv * (double)gamma[c];
        double sh  = (double)beta[c] - mu * sc;
        scale[c] = (float)sc;
        shift[c] = (float)sh;
    }
}

// ---- dom_out finalize pass A: write outdom, flag borderline rows -----------
__global__ __launch_bounds__(256)
void domfinal_a(const double* __restrict__ domacc, const float* __restrict__ bd2,
                float* __restrict__ outdom, int* __restrict__ fixmeta, int* __restrict__ fixlist)
{
    int r = blockIdx.x * 256 + threadIdx.x;
    double v0 = domacc[(size_t)r * 3 + 0] + (double)bd2[0];
    double v1 = domacc[(size_t)r * 3 + 1] + (double)bd2[1];
    double v2 = domacc[(size_t)r * 3 + 2] + (double)bd2[2];
    outdom[(size_t)r * 3 + 0] = (float)v0;
    outdom[(size_t)r * 3 + 1] = (float)v1;
    outdom[(size_t)r * 3 + 2] = (float)v2;
    double mx01 = v0 > v1 ? v0 : v1, mn01 = v0 > v1 ? v1 : v0;
    double best = mx01 > v2 ? mx01 : v2;
    double m2   = mx01 > v2 ? (mn01 > v2 ? mn01 : v2) : mx01;
    if (best - m2 < 1.5e-2) {
        int p = atomicAdd(fixmeta, 1);
        fixlist[p] = r;
    }
}

// ---------------------------------------------------------------------------
// fixrow split across BLOCKS (unchanged from r18).
// ---------------------------------------------------------------------------
__global__ __launch_bounds__(256)
void fx_s1(const int* __restrict__ fixmeta, const int* __restrict__ fixlist,
           const float* __restrict__ x, const float* __restrict__ W1,
           float* __restrict__ hfix)
{
    int nfix = fixmeta[0]; if (nfix > FCAP) nfix = FCAP;
    __shared__ float xs[FR][200];
    int tid = threadIdx.x;
    int n0 = tid * 3;
    int p = blockIdx.x & 3, k0 = p * 196;
    int cstep = (gridDim.x >> 2) * FR;
    for (int base = (blockIdx.x >> 2) * FR; base < nfix; base += cstep) {
        int nr = nfix - base; if (nr > FR) nr = FR;
        __syncthreads();
        for (int i = tid; i < FR * 196; i += 256) {
            int rr = i / 196, cc = i - rr * 196;
            int row = fixlist[base + (rr < nr ? rr : nr - 1)];
            xs[rr][cc] = x[(size_t)row * KIN + k0 + cc];
        }
        __syncthreads();
        float acc[FR][3];
        #pragma unroll
        for (int r = 0; r < FR; r++) { acc[r][0]=0.f; acc[r][1]=0.f; acc[r][2]=0.f; }
        for (int kk = 0; kk < 196; kk++) {
            int k = k0 + kk;
            float w0 = W1[(size_t)k * HD + n0];
            float w1 = W1[(size_t)k * HD + n0 + 1];
            float w2 = W1[(size_t)k * HD + n0 + 2];
            #pragma unroll
            for (int r = 0; r < FR; r++) {
                float xv = xs[r][kk];
                acc[r][0] += xv * w0; acc[r][1] += xv * w1; acc[r][2] += xv * w2;
            }
        }
        for (int r = 0; r < nr; r++) {
            atomicAdd(&hfix[(size_t)(base + r) * HD + n0],     acc[r][0]);
            atomicAdd(&hfix[(size_t)(base + r) * HD + n0 + 1], acc[r][1]);
            atomicAdd(&hfix[(size_t)(base + r) * HD + n0 + 2], acc[r][2]);
        }
    }
}

__global__ __launch_bounds__(256)
void fx_s2(const int* __restrict__ fixmeta,
           const float* __restrict__ hfix,
           const float* __restrict__ b1, const float* __restrict__ scale,
           const float* __restrict__ shift,
           const float* __restrict__ Wd1, float* __restrict__ h2fix)
{
    int nfix = fixmeta[0]; if (nfix > FCAP) nfix = FCAP;
    __shared__ float ft[FR][196];
    int tid = threadIdx.x;
    int n0 = tid * 3;
    int p = blockIdx.x & 3, k0 = p * 192;
    int cstep = (gridDim.x >> 2) * FR;
    for (int base = (blockIdx.x >> 2) * FR; base < nfix; base += cstep) {
        int nr = nfix - base; if (nr > FR) nr = FR;
        __syncthreads();
        for (int i = tid; i < FR * 192; i += 256) {
            int rr = i / 192, cc = i - rr * 192;
            int k = k0 + cc;
            int fp = base + (rr < nr ? rr : nr - 1);
            ft[rr][cc] = frelu((hfix[(size_t)fp * HD + k] + b1[k]) * scale[k] + shift[k]);
        }
        __syncthreads();
        float acc[FR][3];
        #pragma unroll
        for (int r = 0; r < FR; r++) { acc[r][0]=0.f; acc[r][1]=0.f; acc[r][2]=0.f; }
        for (int kk = 0; kk < 192; kk++) {
            int k = k0 + kk;
            float w0 = Wd1[(size_t)k * HD + n0];
            float w1 = Wd1[(size_t)k * HD + n0 + 1];
            float w2 = Wd1[(size_t)k * HD + n0 + 2];
            #pragma unroll
            for (int r = 0; r < FR; r++) {
                float fv = ft[r][kk];
                acc[r][0] += fv * w0; acc[r][1] += fv * w1; acc[r][2] += fv * w2;
            }
        }
        for (int r = 0; r < nr; r++) {
            atomicAdd(&h2fix[(size_t)(base + r) * HD + n0],     acc[r][0]);
            atomicAdd(&h2fix[(size_t)(base + r) * HD + n0 + 1], acc[r][1]);
            atomicAdd(&h2fix[(size_t)(base + r) * HD + n0 + 2], acc[r][2]);
        }
    }
}

__global__ __launch_bounds__(256)
void fx_fin(const int* __restrict__ fixmeta, const int* __restrict__ fixlist,
            const float* __restrict__ h2fix,
            const float* __restrict__ bd1, const float* __restrict__ Wd2,
            const float* __restrict__ bd2, float* __restrict__ outdom)
{
    int nfix = fixmeta[0]; if (nfix > FCAP) nfix = FCAP;
    int tid = threadIdx.x, lane = tid & 63, wid = tid >> 6;
    for (int fp = blockIdx.x * 4 + wid; fp < nfix; fp += gridDim.x * 4) {
        int kb = lane * 12;
        float y0 = 0.f, y1 = 0.f, y2 = 0.f;
        #pragma unroll
        for (int j = 0; j < 12; j++) {
            int k = kb + j;
            float hh = frelu(h2fix[(size_t)fp * HD + k] + bd1[k]);
            y0 += hh * Wd2[k * 3 + 0];
            y1 += hh * Wd2[k * 3 + 1];
            y2 += hh * Wd2[k * 3 + 2];
        }
        #pragma unroll
        for (int m = 1; m < 64; m <<= 1) {
            y0 += __shfl_xor(y0, m, 64);
            y1 += __shfl_xor(y1, m, 64);
            y2 += __shfl_xor(y2, m, 64);
        }
        if (lane == 0) {
            int row = fixlist[fp];
            outdom[(size_t)row * 3 + 0] = y0 + bd2[0];
            outdom[(size_t)row * 3 + 1] = y1 + bd2[1];
            outdom[(size_t)row * 3 + 2] = y2 + bd2[2];
        }
    }
}

// ---- pass B: argmax + bucket (block-aggregated atomics) --------------------
__global__ __launch_bounds__(256)
void domfinal_b(const float* __restrict__ outdom, int* __restrict__ cnt, int* __restrict__ lists)
{
    __shared__ int lcnt[3], base[3];
    int tid = threadIdx.x;
    if (tid < 3) lcnt[tid] = 0;
    __syncthreads();
    int r = blockIdx.x * 256 + tid;
    float v0 = outdom[(size_t)r * 3 + 0];
    float v1 = outdom[(size_t)r * 3 + 1];
    float v2 = outdom[(size_t)r * 3 + 2];
    int p = 0; float best = v0;
    if (v1 > best) { best = v1; p = 1; }
    if (v2 > best) { best = v2; p = 2; }
    int lpos = atomicAdd(&lcnt[p], 1);
    __syncthreads();
    if (tid < 3) base[tid] = atomicAdd(&cnt[tid], lcnt[tid]);
    __syncthreads();
    lists[(size_t)p * BATCH + base[p] + lpos] = r;
}

// ---- expert via MFMA: 128 gathered rows x 64(E) x K=768 per block ----------
__global__ __launch_bounds__(256)
void expert_mfma(const unsigned short* __restrict__ fbf,
                 const char* __restrict__ WaC,
                 const int* __restrict__ cnt, const int* __restrict__ lists,
                 const float* __restrict__ ba,
                 const float* __restrict__ Wb, const float* __restrict__ bb,
                 float* __restrict__ outs)
{
    __shared__ __align__(16) char sm[12288];
    __shared__ float hid[128][66];
    __shared__ int rowidx[128];

    int d = blockIdx.y;
    int count = cnt[d];
    int start = blockIdx.x * 128;
    if (start >= count) return;
    int nrows = count - start; if (nrows > 128) nrows = 128;

    int tid = threadIdx.x;
    int lane = tid & 63, wid = tid >> 6;
    int l15 = lane & 15, l4 = lane >> 4;

    if (tid < 128) {
        int i = tid < nrows ? tid : nrows - 1;
        rowidx[tid] = lists[(size_t)d * BATCH + start + i];
    }
    __syncthreads();

    int asl[2], arow[2];
    #pragma unroll
    for (int q = 0; q < 2; q++) {
        int idx = q * 256 + tid;
        int r = idx >> 2, p = idx & 3;
        asl[q] = (p ^ ((r >> 1) & 3)) & 3;
        arow[q] = rowidx[r];
    }

    int aoff[2], boff[4];
    #pragma unroll
    for (int i2 = 0; i2 < 2; i2++) {
        int ra = wid * 32 + i2 * 16 + l15;
        aoff[i2] = ra * 64 + (((l4 ^ (ra >> 1)) & 3) << 4);
    }
    #pragma unroll
    for (int f = 0; f < 4; f++) {
        int rb = f * 16 + l15;
        boff[f] = rb * 64 + (((l4 ^ (rb >> 1)) & 3) << 4);
    }

    f32x4 acc[2][4];
    #pragma unroll
    for (int i = 0; i < 2; i++)
        #pragma unroll
        for (int j = 0; j < 4; j++) acc[i][j] = (f32x4){0.f, 0.f, 0.f, 0.f};

    for (int t = 0; t < 24; t++) {
        #pragma unroll
        for (int q = 0; q < 2; q++)
            gload16(fbf + (size_t)arow[q] * HD + t * 32 + asl[q] * 8,
                    sm + (q * 256 + tid) * 16);
        gload16(WaC + (size_t)(d * 24 + t) * 4096 + tid * 16, sm + 8192 + tid * 16);
        __syncthreads();
        s16x8 fa[2], fb[4];
        #pragma unroll
        for (int i2 = 0; i2 < 2; i2++) fa[i2] = *(const s16x8*)(sm + aoff[i2]);
        #pragma unroll
        for (int f = 0; f < 4; f++)    fb[f]  = *(const s16x8*)(sm + 8192 + boff[f]);
        #pragma unroll
        for (int i2 = 0; i2 < 2; i2++)
            #pragma unroll
            for (int f = 0; f < 4; f++)
                acc[i2][f] = __builtin_amdgcn_mfma_f32_16x16x32_bf16(fa[i2], fb[f], acc[i2][f], 0, 0, 0);
        __syncthreads();
    }

    #pragma unroll
    for (int i2 = 0; i2 < 2; i2++)
        #pragma unroll
        for (int f = 0; f < 4; f++) {
            int col = f * 16 + l15;
            float bav = ba[d * 64 + col];
            #pragma unroll
            for (int j = 0; j < 4; j++) {
                int row = wid * 32 + i2 * 16 + l4 * 4 + j;
                hid[row][col] = frelu(acc[i2][f][j] + bav);
            }
        }
    __syncthreads();

    for (int o = tid; o < 1280; o += 256) {
        int r2 = o / 10, c = o - r2 * 10;
        if (r2 < nrows) {
            float s = 0.f;
            #pragma unroll 16
            for (int l = 0; l < 64; l++) s += hid[r2][l] * Wb[((size_t)d * 64 + l) * 10 + c];
            outs[(size_t)rowidx[r2] * 10 + c] = s + bb[d * 10 + c];
        }
    }
}

// ---------------------------------------------------------------------------
extern "C" void kernel_launch(void* const* d_in, const int* in_sizes, int n_in,
                              void* d_out, int out_size, void* d_ws, size_t ws_size,
                              hipStream_t stream)
{
    const float* x     = (const float*)d_in[0];
    const float* W1    = (const float*)d_in[1];
    const float* b1    = (const float*)d_in[2];
    const float* gamma = (const float*)d_in[3];
    const float* beta  = (const float*)d_in[4];
    const float* Wd1   = (const float*)d_in[5];
    const float* bd1   = (const float*)d_in[6];
    const float* Wd2   = (const float*)d_in[7];
    const float* bd2   = (const float*)d_in[8];
    const float* Wa    = (const float*)d_in[9];
    const float* ba    = (const float*)d_in[10];
    const float* Wb    = (const float*)d_in[11];
    const float* bb    = (const float*)d_in[12];

    float* out    = (float*)d_out;
    float* outs   = out;
    float* outdom = out + (size_t)BATCH * 10;

    const int NT1 = 25, NT2 = 24;

    char* ws = (char*)d_ws;
    size_t off = 0;
    unsigned short* hbf = (unsigned short*)(ws + off); off += (size_t)BATCH * HD * 2;
    unsigned short* xbf = (unsigned short*)(ws + off); off += (size_t)BATCH * 800 * 2;
    unsigned short* fbf = xbf;   // alias: xbf dead after GEMM1
    float* hfix  = (float*)hbf;  // hbf dead after featBN; exactly 2*FCAP*768*4B
    float* h2fix = hfix + (size_t)FCAP * HD;
    char*  W1hC   = ws + off;            off += (size_t)6 * NT1 * 8192;
    char*  Wd1hC  = ws + off;            off += (size_t)6 * NT2 * 8192;
    char*  WaC    = ws + off;            off += (size_t)3 * 24 * 4096;
    float* sp1    = (float*)(ws + off);  off += (size_t)HD * 1024 * 4;
    float* sp2    = (float*)(ws + off);  off += (size_t)HD * 1024 * 4;
    float* scale  = (float*)(ws + off);  off += HD * 4;
    float* shift  = (float*)(ws + off);  off += HD * 4;
    size_t zoff = off;
    double* domacc = (double*)(ws + off); off += (size_t)BATCH * 3 * 8;
    int*    cnt    = (int*)(ws + off);    off += 64;
    int*    fixmeta= (int*)(ws + off);    off += 64;
    size_t zbytes = off - zoff;
    int*    lists  = (int*)(ws + off);    off += (size_t)3 * BATCH * 4;
    int*    fixlist= (int*)(ws + off);    off += (size_t)BATCH * 4;

    hipMemsetAsync(ws + zoff, 0, zbytes, stream);

    tileW<<<6 * NT1, 256, 0, stream>>>(W1, W1hC, KIN, HD, NT1);
    tileW<<<6 * NT2, 256, 0, stream>>>(Wd1, Wd1hC, HD, HD, NT2);
    tileWa<<<72, 256, 0, stream>>>(Wa, WaC);
    cvtX<<<BATCH * 100 / 256, 256, 0, stream>>>(x, xbf);

    gemm97<0><<<3072, 256, 0, stream>>>(xbf, W1hC, b1, hbf,
                                        nullptr, nullptr, sp1, sp2, 800, NT1);
    bnfinal<<<HD, 256, 0, stream>>>(sp1, sp2, gamma, beta, scale, shift);
    featBN<<<BATCH * 96 / 256, 256, 0, stream>>>(hbf, scale, shift, fbf);
    hipMemsetAsync(hfix, 0, (size_t)2 * FCAP * HD * 4, stream);
    gemm97<1><<<3072, 256, 0, stream>>>(fbf, Wd1hC, bd1, nullptr,
                                        Wd2, domacc, nullptr, nullptr, HD, NT2);
    domfinal_a<<<BATCH / 256, 256, 0, stream>>>(domacc, bd2, outdom, fixmeta, fixlist);
    fx_s1<<<8192, 256, 0, stream>>>(fixmeta, fixlist, x, W1, hfix);
    fx_s2<<<8192, 256, 0, stream>>>(fixmeta, hfix, b1, scale, shift, Wd1, h2fix);
    fx_fin<<<512, 256, 0, stream>>>(fixmeta, fixlist, h2fix, bd1, Wd2, bd2, outdom);
    domfinal_b<<<BATCH / 256, 256, 0, stream>>>(outdom, cnt, lists);
    dim3 eg(512, 3);
    expert_mfma<<<eg, 256, 0, stream>>>(fbf, WaC, cnt, lists, ba, Wb, bb, outs);
}